// Round 2
// baseline (118.056 us; speedup 1.0000x reference)
//
#include <hip/hip_runtime.h>
#include <hip/hip_bf16.h>

#define B_ 128
#define T_ 256
#define D_ 1024
#define L_ 48
#define SMALL_ (-1000.0f)

typedef float f32x4 __attribute__((ext_vector_type(4)));
typedef short bf16x8 __attribute__((ext_vector_type(8)));
typedef unsigned u32x4 __attribute__((ext_vector_type(4)));

__device__ __forceinline__ float bcast(float v, int lane) {
    return __uint_as_float(__builtin_amdgcn_readlane(__float_as_uint(v), lane));
}

// pack two f32 -> one u32 of 2x bf16 (low = lo, high = hi), 1 VALU instr
__device__ __forceinline__ unsigned cvt_pk_bf16(float lo, float hi) {
    unsigned r;
    asm("v_cvt_pk_bf16_f32 %0, %1, %2" : "=v"(r) : "v"(lo), "v"(hi));
    return r;
}

// ---------- Kernel 1: W f32 -> bf16, + zero the reduction ticket ----------
__global__ __launch_bounds__(256) void wconv_kernel(const float* __restrict__ W,
                                                    unsigned short* __restrict__ wbf,
                                                    unsigned* __restrict__ cnt) {
    int i = blockIdx.x * 256 + threadIdx.x;  // grid covers 48*1024 = 49152
    if (i == 0) *cnt = 0u;
    unsigned u = __float_as_uint(W[i]);
    wbf[i] = (unsigned short)((u + 0x7FFFu + ((u >> 16) & 1u)) >> 16);
}

// ---------- Kernel 2: pred = x @ W^T + b  via bf16 MFMA, no LDS ----------
__global__ __launch_bounds__(256) void gemm_kernel(const float* __restrict__ x,
                                                   const unsigned short* __restrict__ wbf,
                                                   const float* __restrict__ bias,
                                                   float* __restrict__ pred) {
    const int wave = threadIdx.x >> 6;
    const int lane = threadIdx.x & 63;
    const int m0 = blockIdx.x * 64 + wave * 16;   // grid 512 blocks -> 32768 rows
    const int l16 = lane & 15;
    const int lg  = lane >> 4;                     // k-group 0..3

    const float* xrow = x + (size_t)(m0 + l16) * D_ + lg * 8;
    f32x4 acc0 = {0.f,0.f,0.f,0.f}, acc1 = {0.f,0.f,0.f,0.f}, acc2 = {0.f,0.f,0.f,0.f};

    #pragma unroll 4
    for (int k0 = 0; k0 < D_; k0 += 32) {
        float4 xa = *reinterpret_cast<const float4*>(xrow + k0);
        float4 xb = *reinterpret_cast<const float4*>(xrow + k0 + 4);
        u32x4 au;
        au[0] = cvt_pk_bf16(xa.x, xa.y);
        au[1] = cvt_pk_bf16(xa.z, xa.w);
        au[2] = cvt_pk_bf16(xb.x, xb.y);
        au[3] = cvt_pk_bf16(xb.z, xb.w);
        bf16x8 af = __builtin_bit_cast(bf16x8, au);
        const unsigned short* wp = wbf + (size_t)l16 * D_ + k0 + lg * 8;
        bf16x8 b0 = *reinterpret_cast<const bf16x8*>(wp);
        bf16x8 b1 = *reinterpret_cast<const bf16x8*>(wp + 16 * D_);
        bf16x8 b2 = *reinterpret_cast<const bf16x8*>(wp + 32 * D_);
        acc0 = __builtin_amdgcn_mfma_f32_16x16x32_bf16(af, b0, acc0, 0, 0, 0);
        acc1 = __builtin_amdgcn_mfma_f32_16x16x32_bf16(af, b1, acc1, 0, 0, 0);
        acc2 = __builtin_amdgcn_mfma_f32_16x16x32_bf16(af, b2, acc2, 0, 0, 0);
    }

    // C layout (verified): col = lane&15, row = (lane>>4)*4 + reg
    const int rbase = m0 + lg * 4;
    float bi0 = bias[l16], bi1 = bias[16 + l16], bi2 = bias[32 + l16];
    #pragma unroll
    for (int r = 0; r < 4; ++r) {
        size_t ro = (size_t)(rbase + r) * L_;
        pred[ro + l16]      = acc0[r] + bi0;
        pred[ro + 16 + l16] = acc1[r] + bi1;
        pred[ro + 32 + l16] = acc2[r] + bi2;
    }
}

// ---------- Kernel 3: CRF forward recursion (linear space) + gold score + fused reduce ----------
__global__ __launch_bounds__(64) void crf_kernel(const float* __restrict__ pred,
                                                 const float* __restrict__ trans,
                                                 const int* __restrict__ tags,
                                                 const int* __restrict__ seq_len,
                                                 float* __restrict__ res,
                                                 unsigned* __restrict__ cnt,
                                                 float* __restrict__ out) {
    const int b = blockIdx.x;
    const int j = threadIdx.x;        // lane
    const int jj = (j < L_) ? j : (L_ - 1);
    const int n = seq_len[b];         // 1..256

    // E column in LINEAR space: E[i] = exp(trans[i][jj])
    float E[48];
    #pragma unroll
    for (int i = 0; i < 48; ++i) E[i] = __expf(trans[i * L_ + jj]);

    const int* tg = tags + b * T_;
    const float* pb = pred + (size_t)b * T_ * L_;

    // ---- gold-path score (lane-parallel over t) ----
    float sc = 0.f;
    for (int t = j; t < n; t += 64) {
        int tag = tg[t];
        int pt = (t == 0) ? (L_ - 2) : tg[t - 1];
        sc += pb[t * L_ + tag] + trans[pt * L_ + tag];
    }
    if (j == 0) sc += trans[tg[n - 1] * L_ + (L_ - 1)];
    #pragma unroll
    for (int o = 32; o > 0; o >>= 1) sc += __shfl_xor(sc, o, 64);

    // ---- forward recursion, linear space with periodic rescale ----
    const bool em = (j < L_ - 2);
    float a = (j == (L_ - 2)) ? 1.f : 0.f;   // exp(alpha) normalized
    float M = 0.f;                            // running log-offset
    float xe = __expf(em ? pb[j] : SMALL_);              // emission exp, step 1
    float nx = (em && n > 1) ? pb[L_ + j] : SMALL_;      // raw emission, step 2

    for (int s = 1; s <= n; ++s) {
        float ldn = SMALL_;                               // prefetch for step s+2
        if (em && s + 1 < n) ldn = pb[(s + 1) * L_ + j];

        float a0 = 0.f, a1 = 0.f, a2 = 0.f, a3 = 0.f;
        #pragma unroll
        for (int i = 0; i < 48; i += 4) {
            a0 = fmaf(bcast(a, i + 0), E[i + 0], a0);
            a1 = fmaf(bcast(a, i + 1), E[i + 1], a1);
            a2 = fmaf(bcast(a, i + 2), E[i + 2], a2);
            a3 = fmaf(bcast(a, i + 3), E[i + 3], a3);
        }
        float raw = (a0 + a1) + (a2 + a3);   // strictly positive at lane 0..47
        if ((s & 7) == 0) {                  // periodic renormalization
            float r = bcast(raw, 0);
            raw *= __builtin_amdgcn_rcpf(r);
            M += __logf(r);
        }
        a = raw * xe;
        xe = __expf(nx);
        nx = ldn;
    }

    // final transition-to-end step: emission exp = 1 at L-1, 0 elsewhere
    {
        float a0 = 0.f, a1 = 0.f, a2 = 0.f, a3 = 0.f;
        #pragma unroll
        for (int i = 0; i < 48; i += 4) {
            a0 = fmaf(bcast(a, i + 0), E[i + 0], a0);
            a1 = fmaf(bcast(a, i + 1), E[i + 1], a1);
            a2 = fmaf(bcast(a, i + 2), E[i + 2], a2);
            a3 = fmaf(bcast(a, i + 3), E[i + 3], a3);
        }
        float raw = (a0 + a1) + (a2 + a3);
        float lz = __logf(raw);              // only lane L-1's value matters
        float v = bcast(lz, L_ - 1);
        if (j == 0) res[b] = v + M - sc;
    }

    // ---- fused deterministic reduce: last block sums all 128 in fixed order ----
    __threadfence();
    int old = -1;
    if (j == 0) old = (int)atomicAdd(cnt, 1u);
    old = __builtin_amdgcn_readlane(old, 0);
    if (old == B_ - 1) {
        __threadfence();
        volatile const float* vr = res;
        float v2 = vr[j] + vr[64 + j];
        #pragma unroll
        for (int o = 32; o > 0; o >>= 1) v2 += __shfl_xor(v2, o, 64);
        if (j == 0) out[0] = v2;
    }
}

extern "C" void kernel_launch(void* const* d_in, const int* in_sizes, int n_in,
                              void* d_out, int out_size, void* d_ws, size_t ws_size,
                              hipStream_t stream) {
    const float* x      = (const float*)d_in[0];
    const float* W      = (const float*)d_in[1];
    const float* bias   = (const float*)d_in[2];
    const float* trans  = (const float*)d_in[3];
    const int*   tags   = (const int*)d_in[4];
    const int*   seqlen = (const int*)d_in[5];
    float* out = (float*)d_out;

    // workspace layout
    float* pred = (float*)d_ws;                                      // 32768*48*4 = 6291456 B
    unsigned short* wbf = (unsigned short*)((char*)d_ws + 6291456);  // 49152*2 = 98304 B
    float* res = (float*)((char*)d_ws + 6389760);                    // 128*4 B
    unsigned* cnt = (unsigned*)((char*)d_ws + 6389760 + 512);        // 4 B

    hipLaunchKernelGGL(wconv_kernel, dim3(192), dim3(256), 0, stream, W, wbf, cnt);
    hipLaunchKernelGGL(gemm_kernel, dim3(512), dim3(256), 0, stream, x, wbf, bias, pred);
    hipLaunchKernelGGL(crf_kernel, dim3(B_), dim3(64), 0, stream, pred, trans, tags, seqlen, res, cnt, out);
}

// Round 4
// 105.187 us; speedup vs baseline: 1.1223x; 1.1223x over previous
//
#include <hip/hip_runtime.h>
#include <hip/hip_bf16.h>

#define B_ 128
#define T_ 256
#define D_ 1024
#define L_ 48
#define SMALL_ (-1000.0f)

typedef float f32x4 __attribute__((ext_vector_type(4)));
typedef short bf16x8 __attribute__((ext_vector_type(8)));
typedef unsigned u32x4 __attribute__((ext_vector_type(4)));

__device__ __forceinline__ float bcastf(float v, int lane) {
    return __uint_as_float(__builtin_amdgcn_readlane(__float_as_uint(v), lane));
}
__device__ __forceinline__ unsigned cvt_pk_bf16(float lo, float hi) {
    unsigned r;
    asm("v_cvt_pk_bf16_f32 %0, %1, %2" : "=v"(r) : "v"(lo), "v"(hi));
    return r;
}

// ---------- Kernel 1: W f32 -> bf16, + zero the reduction ticket ----------
__global__ __launch_bounds__(256) void wconv_kernel(const float* __restrict__ W,
                                                    unsigned short* __restrict__ wbf,
                                                    unsigned* __restrict__ cnt) {
    int i = blockIdx.x * 256 + threadIdx.x;  // 48*1024 = 49152
    if (i == 0) *cnt = 0u;
    unsigned u = __float_as_uint(W[i]);
    wbf[i] = (unsigned short)((u + 0x7FFFu + ((u >> 16) & 1u)) >> 16);
}

// ---------- Kernel 2: pred = x @ W^T + b, bf16 MFMA, 2-way K-split ----------
__global__ __launch_bounds__(256, 4) void gemm_kernel(const float* __restrict__ x,
                                                      const unsigned short* __restrict__ wbf,
                                                      const float* __restrict__ bias,
                                                      float* __restrict__ pred) {
    __shared__ float red[2][64][12];
    const int wv = threadIdx.x >> 6;
    const int lane = threadIdx.x & 63;
    const int pair = wv >> 1;        // which 16-row tile
    const int kh = wv & 1;           // which K half
    const int m0 = blockIdx.x * 32 + pair * 16;   // grid 1024 -> 32768 rows
    const int l16 = lane & 15;
    const int lg  = lane >> 4;

    const float* xrow = x + (size_t)(m0 + l16) * D_ + kh * 512 + lg * 8;
    const unsigned short* wrow = wbf + (size_t)l16 * D_ + kh * 512 + lg * 8;
    f32x4 acc0 = {0.f,0.f,0.f,0.f}, acc1 = {0.f,0.f,0.f,0.f}, acc2 = {0.f,0.f,0.f,0.f};

    #pragma unroll 8
    for (int k0 = 0; k0 < 512; k0 += 32) {
        float4 xa = *reinterpret_cast<const float4*>(xrow + k0);
        float4 xb = *reinterpret_cast<const float4*>(xrow + k0 + 4);
        u32x4 au;
        au[0] = cvt_pk_bf16(xa.x, xa.y);
        au[1] = cvt_pk_bf16(xa.z, xa.w);
        au[2] = cvt_pk_bf16(xb.x, xb.y);
        au[3] = cvt_pk_bf16(xb.z, xb.w);
        bf16x8 af = __builtin_bit_cast(bf16x8, au);
        const unsigned short* wp = wrow + k0;
        bf16x8 b0 = *reinterpret_cast<const bf16x8*>(wp);
        bf16x8 b1 = *reinterpret_cast<const bf16x8*>(wp + 16 * D_);
        bf16x8 b2 = *reinterpret_cast<const bf16x8*>(wp + 32 * D_);
        acc0 = __builtin_amdgcn_mfma_f32_16x16x32_bf16(af, b0, acc0, 0, 0, 0);
        acc1 = __builtin_amdgcn_mfma_f32_16x16x32_bf16(af, b1, acc1, 0, 0, 0);
        acc2 = __builtin_amdgcn_mfma_f32_16x16x32_bf16(af, b2, acc2, 0, 0, 0);
    }

    if (kh == 1) {
        #pragma unroll
        for (int r = 0; r < 4; ++r) {
            red[pair][lane][r]     = acc0[r];
            red[pair][lane][4 + r] = acc1[r];
            red[pair][lane][8 + r] = acc2[r];
        }
    }
    __syncthreads();
    if (kh == 0) {
        const int rbase = m0 + lg * 4;
        float bi0 = bias[l16], bi1 = bias[16 + l16], bi2 = bias[32 + l16];
        #pragma unroll
        for (int r = 0; r < 4; ++r) {
            size_t ro = (size_t)(rbase + r) * L_;
            pred[ro + l16]      = acc0[r] + red[pair][lane][r]     + bi0;
            pred[ro + 16 + l16] = acc1[r] + red[pair][lane][4 + r] + bi1;
            pred[ro + 32 + l16] = acc2[r] + red[pair][lane][8 + r] + bi2;
        }
    }
}

// ---------- Kernel 3: CRF forward (f32 linear space, LDS-staged) + gold + fused reduce ----------
__global__ __launch_bounds__(256) void crf_kernel(const float* __restrict__ pred,
                                                  const float* __restrict__ trans,
                                                  const int* __restrict__ tags,
                                                  const int* __restrict__ seq_len,
                                                  float* __restrict__ res,
                                                  unsigned* __restrict__ cnt,
                                                  float* __restrict__ out) {
    __shared__ float elds[T_ * L_];   // 48 KB: pred[b] staged
    __shared__ float s_sc;
    const int b = blockIdx.x;
    const int tid = threadIdx.x;
    const int wv = tid >> 6;
    const int j = tid & 63;
    const int n = seq_len[b];         // 1..256
    const float* pb = pred + (size_t)b * T_ * L_;

    // E column (f32): E[i] = exp(trans[i][jj]) — global loads, no LDS dep
    float E[48];
    if (wv == 0) {
        const int jj = (j < L_) ? j : (L_ - 1);
        #pragma unroll
        for (int i = 0; i < 48; ++i) E[i] = __expf(trans[i * L_ + jj]);
    }

    // stage pred[b] -> LDS (all 4 waves, float4)
    #pragma unroll
    for (int i = 0; i < 12; ++i) {
        int idx = tid + i * 256;                       // float4 index, 3072 total
        float4 v = *reinterpret_cast<const float4*>(pb + (size_t)idx * 4);
        *reinterpret_cast<float4*>(elds + idx * 4) = v;
    }
    __syncthreads();

    if (wv == 1) {
        // ---- gold-path score (reads staged LDS) ----
        const int* tg = tags + b * T_;
        float sc = 0.f;
        for (int t = j; t < n; t += 64) {
            int tag = tg[t];
            int pt = (t == 0) ? (L_ - 2) : tg[t - 1];
            sc += elds[t * L_ + tag] + trans[pt * L_ + tag];
        }
        if (j == 0) sc += trans[tg[n - 1] * L_ + (L_ - 1)];
        #pragma unroll
        for (int o = 32; o > 0; o >>= 1) sc += __shfl_xor(sc, o, 64);
        if (j == 0) s_sc = sc;
    }

    float logz = 0.f;
    if (wv == 0) {
        // ---- forward recursion, f32 linear space, renorm every 8 (R2-proven) ----
        const bool em = (j < L_ - 2);
        const int jsafe = em ? j : 0;
        float a = (j == (L_ - 2)) ? 1.f : 0.f;   // exp(alpha) normalized
        float M = 0.f;                            // running log-offset
        float xe = __expf(em ? elds[j] : SMALL_);            // emission exp, step 1
        float nx = (em && n > 1) ? elds[L_ + j] : SMALL_;    // raw emission, step 2

        for (int s = 1; s <= n; ++s) {
            int pfrow = (s + 1 < n) ? (s + 1) : 0;
            float ldn = elds[pfrow * L_ + jsafe];            // prefetch step s+2

            float a0 = 0.f, a1 = 0.f, a2 = 0.f, a3 = 0.f;
            #pragma unroll
            for (int i = 0; i < 48; i += 4) {
                a0 = fmaf(bcastf(a, i + 0), E[i + 0], a0);
                a1 = fmaf(bcastf(a, i + 1), E[i + 1], a1);
                a2 = fmaf(bcastf(a, i + 2), E[i + 2], a2);
                a3 = fmaf(bcastf(a, i + 3), E[i + 3], a3);
            }
            float raw = (a0 + a1) + (a2 + a3);   // strictly positive
            if ((s & 7) == 0) {                  // periodic renormalization
                float r = bcastf(raw, 0);
                raw *= __builtin_amdgcn_rcpf(r);
                M += __logf(r);
            }
            a = raw * xe;
            xe = __expf(nx);
            nx = (em && s + 1 < n) ? ldn : SMALL_;
        }

        // final transition-to-end: only lane L-1's value matters
        float a0 = 0.f, a1 = 0.f, a2 = 0.f, a3 = 0.f;
        #pragma unroll
        for (int i = 0; i < 48; i += 4) {
            a0 = fmaf(bcastf(a, i + 0), E[i + 0], a0);
            a1 = fmaf(bcastf(a, i + 1), E[i + 1], a1);
            a2 = fmaf(bcastf(a, i + 2), E[i + 2], a2);
            a3 = fmaf(bcastf(a, i + 3), E[i + 3], a3);
        }
        float raw_end = (a0 + a1) + (a2 + a3);
        float vz = bcastf(raw_end, L_ - 1);
        logz = __logf(vz) + M;
    }
    __syncthreads();

    if (wv == 0) {
        if (j == 0) res[b] = logz - s_sc;
        // fused deterministic reduce: last block sums all 128 in fixed order
        __threadfence();
        unsigned old = 0;
        if (j == 0) old = atomicAdd(cnt, 1u);
        old = __builtin_amdgcn_readlane(old, 0);
        if (old == B_ - 1) {
            __threadfence();
            volatile const float* vr = res;
            float v2 = vr[j] + vr[64 + j];
            #pragma unroll
            for (int o = 32; o > 0; o >>= 1) v2 += __shfl_xor(v2, o, 64);
            if (j == 0) out[0] = v2;
        }
    }
}

extern "C" void kernel_launch(void* const* d_in, const int* in_sizes, int n_in,
                              void* d_out, int out_size, void* d_ws, size_t ws_size,
                              hipStream_t stream) {
    const float* x      = (const float*)d_in[0];
    const float* W      = (const float*)d_in[1];
    const float* bias   = (const float*)d_in[2];
    const float* trans  = (const float*)d_in[3];
    const int*   tags   = (const int*)d_in[4];
    const int*   seqlen = (const int*)d_in[5];
    float* out = (float*)d_out;

    float* pred = (float*)d_ws;                                      // 6291456 B
    unsigned short* wbf = (unsigned short*)((char*)d_ws + 6291456);  // 98304 B
    float* res = (float*)((char*)d_ws + 6389760);                    // 512 B
    unsigned* cnt = (unsigned*)((char*)d_ws + 6390272);              // 4 B

    hipLaunchKernelGGL(wconv_kernel, dim3(192), dim3(256), 0, stream, W, wbf, cnt);
    hipLaunchKernelGGL(gemm_kernel, dim3(1024), dim3(256), 0, stream, x, wbf, bias, pred);
    hipLaunchKernelGGL(crf_kernel, dim3(B_), dim3(256), 0, stream, pred, trans, tags, seqlen, res, cnt, out);
}